// Round 9
// baseline (261.561 us; speedup 1.0000x reference)
//
#include <hip/hip_runtime.h>

typedef unsigned short u16;
typedef _Float16 f16;
typedef __attribute__((ext_vector_type(8))) short v8s;
typedef __attribute__((ext_vector_type(4))) short v4s;
typedef __attribute__((ext_vector_type(8))) f16   v8h;
typedef __attribute__((ext_vector_type(4))) float v4f;
typedef __attribute__((ext_vector_type(16))) float v16f;
typedef __attribute__((ext_vector_type(4))) unsigned v4u;

#define NB   8
#define NC   256
#define DQK  32
#define NPIX 4096

__device__ __forceinline__ u16 f2bf(float f) {
  unsigned u = __builtin_bit_cast(unsigned, f);
  u += 0x7FFFu + ((u >> 16) & 1u);   // RNE
  return (u16)(u >> 16);
}
__device__ __forceinline__ u16 f2h(float f) {
  return __builtin_bit_cast(u16, (f16)f);   // v_cvt_f16_f32, RNE
}
__device__ __forceinline__ unsigned cvt_pk_bf16(float lo, float hi) {
  unsigned r;
  asm("v_cvt_pk_bf16_f32 %0, %1, %2" : "=v"(r) : "v"(lo), "v"(hi));
  return r;
}
// raw v_exp_f32: exponents here are in ~[-91,-18] -> normal range, no ocml fixup needed
__device__ __forceinline__ float fast_exp2(float x) {
  float r;
  asm("v_exp_f32 %0, %1" : "=v"(r) : "v"(x));
  return r;
}

// ---- W -> fp16 (layouts already [o][c] row-major, elementwise convert) ----
__global__ __launch_bounds__(256)
void convert_w(const float* __restrict__ Wq, const float* __restrict__ Wk,
               const float* __restrict__ Wv,
               u16* __restrict__ Whq, u16* __restrict__ Whk, u16* __restrict__ Whv) {
  int i = blockIdx.x * 256 + threadIdx.x;   // 0..81919
  if (i < 8192)       Whq[i]         = f2h(Wq[i]);
  else if (i < 16384) Whk[i - 8192]  = f2h(Wk[i - 8192]);
  else                Whv[i - 16384] = f2h(Wv[i - 16384]);
}

// ---- Direct-gather projections: NO LDS, NO barriers (round-7, unchanged) ----
// V output in FRAG-LINEAR layout for the attn kernel's LDS staging:
// u16 index = (((b*64 + (kv>>6))*32 + (ch>>5)*4 + ((kv>>4)&3))*64
//              + ((kv>>3)&1)*32 + (ch&31))*8 + (kv&7)
__global__ __launch_bounds__(256, 2)
void proj_direct(const float* __restrict__ x, const float* __restrict__ y,
                 const u16* __restrict__ Whq, const float* __restrict__ bq,
                 const u16* __restrict__ Whk, const float* __restrict__ bk,
                 const u16* __restrict__ Whv, const float* __restrict__ bv,
                 u16* __restrict__ Qb, u16* __restrict__ Kb, u16* __restrict__ Vt) {
  const int tid = threadIdx.x, w = tid >> 6, lane = tid & 63;
  const int lr = lane & 15, quad = lane >> 4;
  const int b = blockIdx.x & 7;                    // XCD-affine batch
  const int n0 = (blockIdx.x >> 3) * 64;
  const int n = n0 + w * 16 + lr;
  const size_t bn = ((size_t)b << 12) + n;

  const float* __restrict__ xp = x + ((size_t)b << 20) + n;
  const float* __restrict__ yp = y + ((size_t)b << 20) + n;

  v4f aq[2], ak[2], av[16];
#pragma unroll
  for (int ot = 0; ot < 2; ++ot) { aq[ot] = (v4f){0.f,0.f,0.f,0.f}; ak[ot] = (v4f){0.f,0.f,0.f,0.f}; }
#pragma unroll
  for (int vt = 0; vt < 16; ++vt) av[vt] = (v4f){0.f,0.f,0.f,0.f};

#pragma unroll
  for (int cs = 0; cs < 4; ++cs) {
    v8h xb0, xb1, yb0, yb1;
#pragma unroll
    for (int j = 0; j < 8; ++j) {
      const size_t c0 = (size_t)(cs * 64 + quad * 8 + j) * NPIX;
      const size_t c1 = (size_t)(cs * 64 + 32 + quad * 8 + j) * NPIX;
      xb0[j] = (f16)xp[c0];
      xb1[j] = (f16)xp[c1];
      yb0[j] = (f16)yp[c0];
      yb1[j] = (f16)yp[c1];
    }

#pragma unroll
    for (int ot = 0; ot < 2; ++ot) {
      const u16* wqp = Whq + (ot * 16 + lr) * 256 + cs * 64 + quad * 8;
      const u16* wkp = Whk + (ot * 16 + lr) * 256 + cs * 64 + quad * 8;
      aq[ot] = __builtin_amdgcn_mfma_f32_16x16x32_f16(*(const v8h*)(wqp),      xb0, aq[ot], 0, 0, 0);
      aq[ot] = __builtin_amdgcn_mfma_f32_16x16x32_f16(*(const v8h*)(wqp + 32), xb1, aq[ot], 0, 0, 0);
      ak[ot] = __builtin_amdgcn_mfma_f32_16x16x32_f16(*(const v8h*)(wkp),      yb0, ak[ot], 0, 0, 0);
      ak[ot] = __builtin_amdgcn_mfma_f32_16x16x32_f16(*(const v8h*)(wkp + 32), yb1, ak[ot], 0, 0, 0);
    }
#pragma unroll
    for (int vt = 0; vt < 16; ++vt) {
      const u16* wvp = Whv + (vt * 16 + lr) * 256 + cs * 64 + quad * 8;
      av[vt] = __builtin_amdgcn_mfma_f32_16x16x32_f16(*(const v8h*)(wvp),      yb0, av[vt], 0, 0, 0);
      av[vt] = __builtin_amdgcn_mfma_f32_16x16x32_f16(*(const v8h*)(wvp + 32), yb1, av[vt], 0, 0, 0);
    }
  }

#pragma unroll
  for (int ot = 0; ot < 2; ++ot) {
    v4f bqv = *(const v4f*)(bq + ot * 16 + quad * 4);
    v4f bkv = *(const v4f*)(bk + ot * 16 + quad * 4);
    v4s q4, k4;
#pragma unroll
    for (int r = 0; r < 4; ++r) {
      q4[r] = (short)f2h(aq[ot][r] + bqv[r]);
      k4[r] = (short)f2h(ak[ot][r] + bkv[r]);
    }
    *(v4s*)(Qb + bn * DQK + ot * 16 + quad * 4) = q4;
    *(v4s*)(Kb + bn * DQK + ot * 16 + quad * 4) = k4;
  }

#pragma unroll
  for (int vt = 0; vt < 16; ++vt) {
#pragma unroll
    for (int r = 0; r < 4; ++r) {
      int o = vt * 16 + quad * 4 + r;
      size_t off = ((((size_t)b * 64 + (n >> 6)) * 32 + (o >> 5) * 4 + ((n >> 4) & 3)) * 64
                    + ((n >> 3) & 1) * 32 + (o & 31)) * 8 + (n & 7);
      Vt[off] = f2bf(av[vt][r] + bv[o]);
    }
  }
}

// ---- Fused attention: 2 barrier domains per CU ----
// 256-thr blocks (4 waves: wq = w&1 q-subtile, g = w>>1 kv-group), 64 q per
// block, grid 512 = 2 blocks/CU (64.5 KB LDS each).  V tile per step = 32 kv
// x 256 ch = 16 KB, double-buffered per group, 64 steps.  Same proven
// pipeline (counted vmcnt + 1 barrier/step, P in regs via swapped 32x32 S +
// permlane pack); per-acc kv order unchanged.  When one block stalls at its
// barrier, the other block's waves fill the pipes.
#define L2E  1.44269504f
#define SHFT -48.0f

// From S tile (32 kv) produce PV B-frags for its two 16-kv blocks.
// reg r of S: kv = (r&3) + 8*(r>>2) + 4*(lane>>5).
#define PACK_TILE(S, PBLO, PBHI)                                              \
  {                                                                           \
    float e0  = fast_exp2(fmaf(S[0],  L2E, SHFT));                            \
    float e1  = fast_exp2(fmaf(S[1],  L2E, SHFT));                            \
    float e2  = fast_exp2(fmaf(S[2],  L2E, SHFT));                            \
    float e3  = fast_exp2(fmaf(S[3],  L2E, SHFT));                            \
    float e4  = fast_exp2(fmaf(S[4],  L2E, SHFT));                            \
    float e5  = fast_exp2(fmaf(S[5],  L2E, SHFT));                            \
    float e6  = fast_exp2(fmaf(S[6],  L2E, SHFT));                            \
    float e7  = fast_exp2(fmaf(S[7],  L2E, SHFT));                            \
    float e8  = fast_exp2(fmaf(S[8],  L2E, SHFT));                            \
    float e9  = fast_exp2(fmaf(S[9],  L2E, SHFT));                            \
    float e10 = fast_exp2(fmaf(S[10], L2E, SHFT));                            \
    float e11 = fast_exp2(fmaf(S[11], L2E, SHFT));                            \
    float e12 = fast_exp2(fmaf(S[12], L2E, SHFT));                            \
    float e13 = fast_exp2(fmaf(S[13], L2E, SHFT));                            \
    float e14 = fast_exp2(fmaf(S[14], L2E, SHFT));                            \
    float e15 = fast_exp2(fmaf(S[15], L2E, SHFT));                            \
    lsum += (((e0 + e1) + (e2 + e3)) + ((e4 + e5) + (e6 + e7)))               \
          + (((e8 + e9) + (e10 + e11)) + ((e12 + e13) + (e14 + e15)));        \
    unsigned u00 = cvt_pk_bf16(e0,  e1),  u01 = cvt_pk_bf16(e2,  e3);         \
    unsigned u10 = cvt_pk_bf16(e4,  e5),  u11 = cvt_pk_bf16(e6,  e7);         \
    unsigned u20 = cvt_pk_bf16(e8,  e9),  u21 = cvt_pk_bf16(e10, e11);        \
    unsigned u30 = cvt_pk_bf16(e12, e13), u31 = cvt_pk_bf16(e14, e15);        \
    asm("v_permlane32_swap_b32 %0, %1" : "+v"(u00), "+v"(u10));               \
    asm("v_permlane32_swap_b32 %0, %1" : "+v"(u01), "+v"(u11));               \
    asm("v_permlane32_swap_b32 %0, %1" : "+v"(u20), "+v"(u30));               \
    asm("v_permlane32_swap_b32 %0, %1" : "+v"(u21), "+v"(u31));               \
    PBLO = __builtin_bit_cast(v8s, (v4u){u00, u01, u10, u11});                \
    PBHI = __builtin_bit_cast(v8s, (v4u){u20, u21, u30, u31});                \
  }

// Stage the wave's 8 frags of step IT's 16-frag (32kv x 256ch) tile.
// frag-linear: super = IT>>1 (within group range), local frag
// f = ch5*4 + (IT&1)*2 + k2, wave covers ch5 = wq*4 + (j>>1), k2 = j&1.
// Dest slot = ch5*2 + k2 (= wq*8 + j).
#define STAGE(IT, BUF)                                                        \
  {                                                                           \
    _Pragma("unroll")                                                         \
    for (int j = 0; j < 8; ++j) {                                             \
      const size_t f = (size_t)wq * 16 + ((j >> 1) << 2) + (((IT) & 1) << 1) + (j & 1); \
      __builtin_amdgcn_global_load_lds(                                       \
          (const __attribute__((address_space(1))) unsigned*)(Vg + (((size_t)((IT) >> 1) * 32) + f) * 512), \
          (__attribute__((address_space(3))) unsigned*)(&SB[BUF][wq * 8 + j][0][0]), 16, 0, 0); \
    }                                                                         \
  }

__global__ __launch_bounds__(256, 2)
void attn_kernel(const u16* __restrict__ Qb, const u16* __restrict__ Kb,
                 const u16* __restrict__ Vt, float* __restrict__ out) {
  __shared__ __attribute__((aligned(16))) u16 SB[4][16][64][8];   // 64 KiB
  __shared__ float Ls2[2][32];

  const int tid  = threadIdx.x;
  const int w    = tid >> 6;      // 0..3
  const int lane = tid & 63;
  const int l31  = lane & 31;
  const int h    = lane >> 5;
  const int wq   = w & 1;         // q-subtile (2 x 32 q)
  const int g    = w >> 1;        // kv-group (0: kv 0..2047, 1: kv 2048..4095)
  const int bufbase = g * 2;

  const int b  = blockIdx.x & 7;            // XCD-affine batch mapping
  const int q0 = (blockIdx.x >> 3) << 6;    // 64 q per block (grid MUST be 8*64=512)
  const int qw = q0 + wq * 32;              // wave's 32 q

  // Q B-frags (two d-halves): lane holds col q = qw+l31, k = h*8+j
  const u16* Qp = Qb + ((size_t)b * NPIX + qw + l31) * DQK + h * 8;
  const v8h qf0 = *(const v8h*)(Qp);
  const v8h qf1 = *(const v8h*)(Qp + 16);

  // K A-frag base for this group's kv range (step window = it*32 kv)
  const u16* Kp = Kb + ((size_t)b * NPIX + l31) * DQK + h * 8 + (size_t)g * 2048 * DQK;

  // V frag-linear global for this group's kv range
  const u16* Vg = Vt + ((size_t)b << 20) + (size_t)lane * 8 + (size_t)g * 32 * 16384;

  v16f acc[8];
#pragma unroll
  for (int i = 0; i < 8; ++i) acc[i] = (v16f){};
  float lsum = 0.f;
  const v16f vz = (v16f){};

  // ---- prologue: K(0); stage(0); S(0)+pack -> pB; kc <- K(1) ----
  v8h kc0, kc1, kn0, kn1;
  v8s pB0, pB1;
  {
    v8h t0 = *(const v8h*)(Kp);          // K(0) first (so its wait leaves
    v8h t1 = *(const v8h*)(Kp + 16);     // stage(0) in flight)
    STAGE(0, bufbase);
    v16f sA = __builtin_amdgcn_mfma_f32_32x32x16_f16(t0, qf0, vz, 0, 0, 0);
    sA = __builtin_amdgcn_mfma_f32_32x32x16_f16(t1, qf1, sA, 0, 0, 0);
    PACK_TILE(sA, pB0, pB1);
    kc0 = *(const v8h*)(Kp + 1024);
    kc1 = *(const v8h*)(Kp + 1040);
    kn0 = kc0; kn1 = kc1;
  }

  // ---- main loop (64 steps of 32 kv per group) ----
#pragma unroll 1
  for (int it = 0; it < 64; ++it) {
    const int pp = it & 1;
    __builtin_amdgcn_sched_barrier(0);
    if (it < 63) {
      asm volatile("s_waitcnt vmcnt(2)" ::: "memory");   // stage(it) landed; K(it+1) in flight
    } else {
      asm volatile("s_waitcnt vmcnt(0)" ::: "memory");
    }
    __builtin_amdgcn_s_barrier();                        // all waves' stage(it) landed
    __builtin_amdgcn_sched_barrier(0);

    if (it < 63) {   // stage(it+1) into other parity buffer
      STAGE(it + 1, bufbase + (pp ^ 1));
    }

    // PV(it): 16 conflict-free ds_read_b128 + 16 MFMA (8 independent chains)
    __builtin_amdgcn_s_setprio(1);
#pragma unroll
    for (int ct = 0; ct < 8; ++ct) {
      v8s vf0 = *(const v8s*)(&SB[bufbase + pp][ct * 2 + 0][lane][0]);
      v8s vf1 = *(const v8s*)(&SB[bufbase + pp][ct * 2 + 1][lane][0]);
      acc[ct] = __builtin_amdgcn_mfma_f32_32x32x16_bf16(vf0, pB0, acc[ct], 0, 0, 0);
      acc[ct] = __builtin_amdgcn_mfma_f32_32x32x16_bf16(vf1, pB1, acc[ct], 0, 0, 0);
    }
    __builtin_amdgcn_s_setprio(0);

    if (it < 63) {
      // S(it+1) on K(it+1) regs (stage(it+1) stays in flight across this wait)
      v16f sA = __builtin_amdgcn_mfma_f32_32x32x16_f16(kc0, qf0, vz, 0, 0, 0);
      sA = __builtin_amdgcn_mfma_f32_32x32x16_f16(kc1, qf1, sA, 0, 0, 0);
      if (it < 62) {   // K(it+2)
        const u16* kp2 = Kp + (size_t)(it + 2) * 1024;
        kn0 = *(const v8h*)(kp2);
        kn1 = *(const v8h*)(kp2 + 16);
      }
      PACK_TILE(sA, pB0, pB1);
      kc0 = kn0; kc1 = kn1;
    }
  }

  // ---- epilogue: combine kv-groups (pure addition), scale, store ----
  lsum += __shfl_xor(lsum, 32);      // fold h halves; lane's q = l31

  __syncthreads();                   // all PV reads of SB complete -> scratch reuse safe
  float* Cb = (float*)&SB[0][0][0][0];
  if (w >= 2) {
    const int w2 = w - 2;
#pragma unroll
    for (int ct = 0; ct < 8; ++ct)
#pragma unroll
      for (int k = 0; k < 4; ++k) {
        v4f c = {acc[ct][k * 4 + 0], acc[ct][k * 4 + 1],
                 acc[ct][k * 4 + 2], acc[ct][k * 4 + 3]};
        *(v4f*)(Cb + (((w2 * 32 + ct * 4 + k) * 64 + lane) << 2)) = c;   // 64 KB, fits SB
      }
    if (lane < 32) Ls2[w2][l31] = lsum;
  }
  __syncthreads();
  if (w < 2) {
    const float linv = 1.0f / (lsum + Ls2[w][l31]);
#pragma unroll
    for (int ct = 0; ct < 8; ++ct)
#pragma unroll
      for (int k = 0; k < 4; ++k) {
        v4f c = *(const v4f*)(Cb + (((w * 32 + ct * 4 + k) * 64 + lane) << 2));
        acc[ct][k * 4 + 0] += c[0]; acc[ct][k * 4 + 1] += c[1];
        acc[ct][k * 4 + 2] += c[2]; acc[ct][k * 4 + 3] += c[3];
      }

    float* op = out + (size_t)b * NC * NPIX + q0 + w * 32 + l31;
#pragma unroll
    for (int ct = 0; ct < 8; ++ct)
#pragma unroll
      for (int r = 0; r < 16; ++r) {
        const int ch = ct * 32 + (r & 3) + ((r >> 2) << 3) + (h << 2);
        op[(size_t)ch * NPIX] = acc[ct][r] * linv;
      }
  }
}

extern "C" void kernel_launch(void* const* d_in, const int* in_sizes, int n_in,
                              void* d_out, int out_size, void* d_ws, size_t ws_size,
                              hipStream_t stream) {
  const float* x  = (const float*)d_in[0];
  const float* y  = (const float*)d_in[1];
  const float* Wq = (const float*)d_in[2];
  const float* bq = (const float*)d_in[3];
  const float* Wk = (const float*)d_in[4];
  const float* bk = (const float*)d_in[5];
  const float* Wv = (const float*)d_in[6];
  const float* bv = (const float*)d_in[7];
  float* out = (float*)d_out;

  // ws: Qb 2MB | Kb 2MB | Vt 16MB | Whq/Whk/Whv 160KB  ~= 20.2MB
  u16* Qb  = (u16*)d_ws;
  u16* Kb  = Qb + (size_t)NB * NPIX * DQK;
  u16* Vt  = Kb + (size_t)NB * NPIX * DQK;
  u16* Whq = Vt + (size_t)NB * NC * NPIX;
  u16* Whk = Whq + 32 * 256;
  u16* Whv = Whk + 32 * 256;

  hipLaunchKernelGGL(convert_w, dim3(320), dim3(256), 0, stream, Wq, Wk, Wv, Whq, Whk, Whv);
  hipLaunchKernelGGL(proj_direct, dim3(512), dim3(256), 0, stream,
                     x, y, Whq, bq, Whk, bk, Whv, bv, Qb, Kb, Vt);
  hipLaunchKernelGGL(attn_kernel, dim3(512), dim3(256), 0, stream, Qb, Kb, Vt, out);
}